// Round 3
// baseline (190.434 us; speedup 1.0000x reference)
//
#include <hip/hip_runtime.h>
#include <hip/hip_bf16.h>

typedef unsigned int u32;
typedef unsigned short u16;
typedef __attribute__((ext_vector_type(8))) short bf16x8;   // 8 bf16 in 4 VGPRs
typedef __attribute__((ext_vector_type(4))) float f32x4;
typedef __attribute__((ext_vector_type(4))) float f4;

#define DI __device__ __forceinline__

DI u16 f2bfu(float f){
  union{float f; u32 i;} u; u.f = f;
  u32 lsb = (u.i >> 16) & 1u;
  u.i += 0x7fffu + lsb;    // RNE
  return (u16)(u.i >> 16);
}

union BU { uint4 v; bf16x8 s; };

// ---------------- pack W_in into MFMA fragment order (bf16) ----------------
// frag for 16x16x32: lane l holds W[k = (l>>4)*8 + t][n = l&15], t=0..7.
// (A-frag of W^T and B-frag of W have the SAME lane map.)
// Wp3 : [kk 8][nt 16][lane 64][t 8]  <- W3 = W_in[512 + k][n]
// Wp12: [half 2][nt 16][kk 8][lane 64][t 8] <- W_in[half*256 + k][n]
__global__ __launch_bounds__(256) void k_pack(const float* __restrict__ W_in,
                                              u16* __restrict__ Wp3,
                                              u16* __restrict__ Wp12)
{
  int idx = blockIdx.x * 256 + threadIdx.x;   // [0, 24576)
  int l = idx & 63;
  int g = idx >> 6;                            // [0, 384)
  int lq = l >> 4, lr = l & 15;
  u16 o[8];
  if (g < 128){            // W3: g = kk*16 + nt  (kk-major)
    int kk = g >> 4, nt = g & 15;
    int n  = nt * 16 + lr;
    int k0 = 512 + kk * 32 + lq * 8;
#pragma unroll
    for (int tt = 0; tt < 8; tt++) o[tt] = f2bfu(W_in[(size_t)(k0 + tt) * 256 + n]);
    *(uint4*)(Wp3 + (size_t)idx * 8) = *(uint4*)o;
  } else {                 // W12: (g-128) = half*128 + nt*8 + kk
    int g2 = g - 128;
    int half = g2 >> 7, rem = g2 & 127;
    int nt = rem >> 3, kk = rem & 7;
    int n  = nt * 16 + lr;
    int k0 = half * 256 + kk * 32 + lq * 8;
#pragma unroll
    for (int tt = 0; tt < 8; tt++) o[tt] = f2bfu(W_in[(size_t)(k0 + tt) * 256 + n]);
    *(uint4*)(Wp12 + (size_t)g2 * 512 + (size_t)l * 8) = *(uint4*)o;
  }
}

// ---------------- k_pre: P1 = b_in + nodes@W1, P2 = nodes@W2 (bf16 MFMA) ----
// 128 blocks: bid = rt*8 + half*4 + cg.
__global__ __launch_bounds__(256) void k_pre(
    const float* __restrict__ nodes, const float* __restrict__ b_in,
    const u16* __restrict__ Wp12, float* __restrict__ P1, float* __restrict__ P2)
{
  const int t = threadIdx.x;
  const int w = t >> 6, l = t & 63, lq = l >> 4, lr = l & 15;
  const int bid = blockIdx.x;
  const int rt = bid >> 3, half = (bid >> 2) & 1, cg = bid & 3;

  bf16x8 af[8];
  {
    const float* ap = nodes + (size_t)(rt * 64 + 16 * w + lr) * 256 + lq * 8;
#pragma unroll
    for (int kk = 0; kk < 8; kk++){
      float4 x = *(const float4*)(ap + kk * 32);
      float4 y = *(const float4*)(ap + kk * 32 + 4);
      bf16x8 a;
      a[0]=(short)f2bfu(x.x); a[1]=(short)f2bfu(x.y); a[2]=(short)f2bfu(x.z); a[3]=(short)f2bfu(x.w);
      a[4]=(short)f2bfu(y.x); a[5]=(short)f2bfu(y.y); a[6]=(short)f2bfu(y.z); a[7]=(short)f2bfu(y.w);
      af[kk] = a;
    }
  }
  const uint4* wp = (const uint4*)(Wp12 + (size_t)half * 128 * 512);
  float* P = half ? P2 : P1;
#pragma unroll
  for (int ntl = 0; ntl < 4; ntl++){
    const int nt = cg * 4 + ntl;
    f32x4 acc = {0.f, 0.f, 0.f, 0.f};
#pragma unroll
    for (int kk = 0; kk < 8; kk++){
      BU bu; bu.v = wp[(nt * 8 + kk) * 64 + l];
      acc = __builtin_amdgcn_mfma_f32_16x16x32_bf16(af[kk], bu.s, acc, 0, 0, 0);
    }
    const int col = nt * 16 + lr;
    const float bv = half ? 0.f : b_in[col];
#pragma unroll
    for (int r = 0; r < 4; r++){
      const int row = rt * 64 + 16 * w + 4 * lq + r;
      P[(size_t)row * 256 + col] = acc[r] + bv;
    }
  }
}

// ---------------- k_main: one block per (b,i) --------------------------------
// Swapped MFMA (thread owns one j row, 4 consecutive d per nt). Edges bulk-
// loaded upfront (16 loads in flight). Wp3 read per-lane from L2 (no LDS
// staging, no barriers in the MFMA loop). d-columns processed in two halves
// of 128 so only acc[8] is live; residual re-reads h from L2. LDS ~1.6 KB.
__global__ __launch_bounds__(256, 4) void k_main(
    const float* __restrict__ nodes, const float* __restrict__ edges,
    const u16* __restrict__ Wp3, const float* __restrict__ W_coef,
    const float* __restrict__ b_coef, const float* __restrict__ W_out,
    const float* __restrict__ b_out, const float* __restrict__ P1,
    const float* __restrict__ P2, float* __restrict__ out_nodes,
    float* __restrict__ out_h)
{
  __shared__ float coefS[64];
  __shared__ float attnS[64];
  __shared__ float resS[256];

  const int t = threadIdx.x;
  const int w = t >> 6, l = t & 63, lq = l >> 4, lr = l & 15;
  const int bid = blockIdx.x;
  const int bi = ((bid & 7) << 7) | (bid >> 3);   // XCD-chunked swizzle (1024 = 8*128)
  const int b = bi >> 6, i = bi & 63;
  const int j = 16 * w + lr;          // this thread's edge row

  // A-frags: edge row j, all 8 K-chunks issued back-to-back (16 loads in flight)
  bf16x8 af[8];
  {
    const float* ap = edges + (size_t)bi * 16384 + (size_t)j * 256 + lq * 8;
    float4 x[8], y[8];
#pragma unroll
    for (int kk = 0; kk < 8; kk++){
      x[kk] = *(const float4*)(ap + kk * 32);
      y[kk] = *(const float4*)(ap + kk * 32 + 4);
    }
#pragma unroll
    for (int kk = 0; kk < 8; kk++){
      bf16x8 a;
      a[0]=(short)f2bfu(x[kk].x); a[1]=(short)f2bfu(x[kk].y); a[2]=(short)f2bfu(x[kk].z); a[3]=(short)f2bfu(x[kk].w);
      a[4]=(short)f2bfu(y[kk].x); a[5]=(short)f2bfu(y[kk].y); a[6]=(short)f2bfu(y[kk].z); a[7]=(short)f2bfu(y[kk].w);
      af[kk] = a;
    }
  }

  const uint4* wp = (const uint4*)Wp3;
  const float* p1p = P1 + (size_t)bi * 256;
  const float* p2p = P2 + ((size_t)b * 64 + j) * 256;
  float* hop = out_h + ((size_t)bi * 64 + j) * 256;
  float cpart = 0.f;

  for (int half = 0; half < 2; ++half){          // NOT unrolled: keeps acc[8] live-range short
    f32x4 acc[8];
#pragma unroll
    for (int n8 = 0; n8 < 8; n8++) acc[n8] = (f32x4){0.f, 0.f, 0.f, 0.f};
    const uint4* wph = wp + (size_t)half * 8 * 64;   // nt = half*8 + n8
#pragma unroll
    for (int n8 = 0; n8 < 8; n8++){
#pragma unroll
      for (int kk = 0; kk < 8; kk++){
        BU bu; bu.v = wph[(size_t)(kk * 16 + n8) * 64 + l];
        acc[n8] = __builtin_amdgcn_mfma_f32_16x16x32_bf16(bu.s, af[kk], acc[n8], 0, 0, 0);
      }
    }
    // epilogue for these 128 cols: +P1+P2, relu, vectorized h store, coef part
    const int dbase = half * 128;
#pragma unroll
    for (int n8 = 0; n8 < 8; n8++){
      const int d0 = dbase + n8 * 16 + 4 * lq;
      f4 p1v = *(const f4*)(p1p + d0);
      f4 p2v = *(const f4*)(p2p + d0);
      f4 wcv = *(const f4*)(W_coef + d0);
      f4 h;
#pragma unroll
      for (int r = 0; r < 4; r++){
        float xx = acc[n8][r] + p1v[r] + p2v[r];
        h[r] = xx > 0.f ? xx : 0.f;
      }
      *(f4*)(hop + d0) = h;
      cpart += h[0]*wcv[0] + h[1]*wcv[1] + h[2]*wcv[2] + h[3]*wcv[3];
    }
  }

  // coef[j]: sum cpart over the 4 lq groups (lanes l^16, l^32 share j)
  cpart += __shfl_xor(cpart, 16, 64);
  cpart += __shfl_xor(cpart, 32, 64);
  if (lq == 0) coefS[j] = cpart;
  __syncthreads();

  // softmax over j (threads 0..63); b_coef shifts all coefs equally
  if (t < 64){
    int jj = t;
    float val = coefS[jj] + b_coef[0] - (jj == i ? 1e9f : 0.f);
    float m = val;
#pragma unroll
    for (int off = 32; off >= 1; off >>= 1){ float o = __shfl_xor(m, off, 64); m = m > o ? m : o; }
    float e = __expf(val - m);
    float s = e;
#pragma unroll
    for (int off = 32; off >= 1; off >>= 1) s += __shfl_xor(s, off, 64);
    attnS[jj] = e / s;
  }
  __syncthreads();

  // residual[d=t] = sum_j attn[j] * h[j][d]  (h re-read from L2, just written)
  {
    const float* hb = out_h + (size_t)bi * 16384;
    float res = 0.f;
#pragma unroll 8
    for (int jj = 0; jj < 64; jj++) res += attnS[jj] * hb[(size_t)jj * 256 + t];
    resS[t] = res;
  }
  __syncthreads();

  // new_nodes = nodes + relu(res @ W_out + b_out)  (f32)
  {
    const int d = t;
    float acco = b_out[d];
#pragma unroll 8
    for (int k4 = 0; k4 < 64; k4++){
      float4 r4 = *(const float4*)&resS[k4 * 4];
      acco += r4.x * W_out[(size_t)(k4 * 4 + 0) * 256 + d];
      acco += r4.y * W_out[(size_t)(k4 * 4 + 1) * 256 + d];
      acco += r4.z * W_out[(size_t)(k4 * 4 + 2) * 256 + d];
      acco += r4.w * W_out[(size_t)(k4 * 4 + 3) * 256 + d];
    }
    float nv = nodes[(size_t)bi * 256 + d];
    out_nodes[(size_t)bi * 256 + d] = nv + (acco > 0.f ? acco : 0.f);
  }
}

extern "C" void kernel_launch(void* const* d_in, const int* in_sizes, int n_in,
                              void* d_out, int out_size, void* d_ws, size_t ws_size,
                              hipStream_t stream)
{
  const float* nodes  = (const float*)d_in[0];
  const float* edges  = (const float*)d_in[1];
  const float* W_in   = (const float*)d_in[2];
  const float* b_in   = (const float*)d_in[3];
  const float* W_coef = (const float*)d_in[4];
  const float* b_coef = (const float*)d_in[5];
  const float* W_out  = (const float*)d_in[6];
  const float* b_out  = (const float*)d_in[7];
  (void)in_sizes; (void)n_in; (void)out_size; (void)ws_size;

  float* P1  = (float*)d_ws;           // [1024][256] f32
  float* P2  = P1 + 262144;            // [1024][256] f32
  u16*  Wp3  = (u16*)(P2 + 262144);    // 65536 bf16 (128 KB)
  u16*  Wp12 = Wp3 + 65536;            // 131072 bf16 (256 KB)

  float* out_nodes = (float*)d_out;          // [1024*256] f32
  float* out_h = out_nodes + 262144;         // [65536*256] f32

  hipLaunchKernelGGL(k_pack, dim3(96),   dim3(256), 0, stream, W_in, Wp3, Wp12);
  hipLaunchKernelGGL(k_pre,  dim3(128),  dim3(256), 0, stream, nodes, b_in, Wp12, P1, P2);
  hipLaunchKernelGGL(k_main, dim3(1024), dim3(256), 0, stream,
                     nodes, edges, Wp3, W_coef, b_coef, W_out, b_out,
                     P1, P2, out_nodes, out_h);
}

// Round 4
// 178.195 us; speedup vs baseline: 1.0687x; 1.0687x over previous
//
#include <hip/hip_runtime.h>
#include <hip/hip_bf16.h>

typedef unsigned int u32;
typedef unsigned short u16;
typedef __attribute__((ext_vector_type(8))) short bf16x8;   // 8 bf16 in 4 VGPRs
typedef __attribute__((ext_vector_type(4))) float f32x4;
typedef __attribute__((ext_vector_type(4))) float f4;

#define DI __device__ __forceinline__

DI u16 f2bfu(float f){
  union{float f; u32 i;} u; u.f = f;
  u32 lsb = (u.i >> 16) & 1u;
  u.i += 0x7fffu + lsb;    // RNE
  return (u16)(u.i >> 16);
}

union BU { uint4 v; bf16x8 s; };

// async global -> LDS, 16B per lane. lds ptr must be wave-uniform.
DI void gld16(const void* g, void* l){
  __builtin_amdgcn_global_load_lds(
      (const __attribute__((address_space(1))) void*)g,
      (__attribute__((address_space(3))) void*)l, 16, 0, 0);
}

// ---------------- pack W_in into MFMA fragment order (bf16) ----------------
// frag for 16x16x32: lane l holds W[k = (l>>4)*8 + t][n = l&15], t=0..7.
// Wp3 : [nt 16][kk 8][lane 64][t 8]  <- W3 = W_in[512 + k][n]
//       (nt-major: a 2-nt staging chunk = 16 KB contiguous)
// Wp12: [half 2][nt 16][kk 8][lane 64][t 8] <- W_in[half*256 + k][n]
__global__ __launch_bounds__(256) void k_pack(const float* __restrict__ W_in,
                                              u16* __restrict__ Wp3,
                                              u16* __restrict__ Wp12)
{
  int idx = blockIdx.x * 256 + threadIdx.x;   // [0, 24576)
  int l = idx & 63;
  int g = idx >> 6;                            // [0, 384)
  int lq = l >> 4, lr = l & 15;
  u16 o[8];
  if (g < 128){            // W3: g = nt*8 + kk  (nt-major)
    int nt = g >> 3, kk = g & 7;
    int n  = nt * 16 + lr;
    int k0 = 512 + kk * 32 + lq * 8;
#pragma unroll
    for (int tt = 0; tt < 8; tt++) o[tt] = f2bfu(W_in[(size_t)(k0 + tt) * 256 + n]);
    *(uint4*)(Wp3 + (size_t)idx * 8) = *(uint4*)o;
  } else {                 // W12: (g-128) = half*128 + nt*8 + kk
    int g2 = g - 128;
    int half = g2 >> 7, rem = g2 & 127;
    int nt = rem >> 3, kk = rem & 7;
    int n  = nt * 16 + lr;
    int k0 = half * 256 + kk * 32 + lq * 8;
#pragma unroll
    for (int tt = 0; tt < 8; tt++) o[tt] = f2bfu(W_in[(size_t)(k0 + tt) * 256 + n]);
    *(uint4*)(Wp12 + (size_t)g2 * 512 + (size_t)l * 8) = *(uint4*)o;
  }
}

// ---------------- k_pre: P1 = b_in + nodes@W1, P2 = nodes@W2 (bf16 MFMA) ----
__global__ __launch_bounds__(256) void k_pre(
    const float* __restrict__ nodes, const float* __restrict__ b_in,
    const u16* __restrict__ Wp12, float* __restrict__ P1, float* __restrict__ P2)
{
  const int t = threadIdx.x;
  const int w = t >> 6, l = t & 63, lq = l >> 4, lr = l & 15;
  const int bid = blockIdx.x;
  const int rt = bid >> 3, half = (bid >> 2) & 1, cg = bid & 3;

  bf16x8 af[8];
  {
    const float* ap = nodes + (size_t)(rt * 64 + 16 * w + lr) * 256 + lq * 8;
#pragma unroll
    for (int kk = 0; kk < 8; kk++){
      float4 x = *(const float4*)(ap + kk * 32);
      float4 y = *(const float4*)(ap + kk * 32 + 4);
      bf16x8 a;
      a[0]=(short)f2bfu(x.x); a[1]=(short)f2bfu(x.y); a[2]=(short)f2bfu(x.z); a[3]=(short)f2bfu(x.w);
      a[4]=(short)f2bfu(y.x); a[5]=(short)f2bfu(y.y); a[6]=(short)f2bfu(y.z); a[7]=(short)f2bfu(y.w);
      af[kk] = a;
    }
  }
  const uint4* wp = (const uint4*)(Wp12 + (size_t)half * 128 * 512);
  float* P = half ? P2 : P1;
#pragma unroll
  for (int ntl = 0; ntl < 4; ntl++){
    const int nt = cg * 4 + ntl;
    f32x4 acc = {0.f, 0.f, 0.f, 0.f};
#pragma unroll
    for (int kk = 0; kk < 8; kk++){
      BU bu; bu.v = wp[(nt * 8 + kk) * 64 + l];
      acc = __builtin_amdgcn_mfma_f32_16x16x32_bf16(af[kk], bu.s, acc, 0, 0, 0);
    }
    const int col = nt * 16 + lr;
    const float bv = half ? 0.f : b_in[col];
#pragma unroll
    for (int r = 0; r < 4; r++){
      const int row = rt * 64 + 16 * w + 4 * lq + r;
      P[(size_t)row * 256 + col] = acc[r] + bv;
    }
  }
}

// ---------------- k_h: GEMM-only. One block per (b,i). ----------------------
// LDS-staged W (2-nt double-buffered chunks, shared across the 4 waves);
// swapped-operand MFMA with CHUNK-LOCAL accumulators (8 VGPR, not 64);
// vectorized epilogue writes h and accumulates coef partials -> coefW.
// No softmax / residual / W_out here.
__global__ __launch_bounds__(256, 3) void k_h(
    const float* __restrict__ edges, const u16* __restrict__ Wp3,
    const float* __restrict__ W_coef, const float* __restrict__ P1,
    const float* __restrict__ P2, float* __restrict__ out_h,
    float* __restrict__ coefW)
{
  __shared__ uint4 wS[2][1024];     // 2 x 16 KB double-buffered W chunks (2 nt each)

  const int t = threadIdx.x;
  const int w = t >> 6, l = t & 63, lq = l >> 4, lr = l & 15;
  const int bid = blockIdx.x;
  const int bi = ((bid & 7) << 7) | (bid >> 3);   // XCD-chunked swizzle
  const int b = bi >> 6;
  const int j = 16 * w + lr;          // this thread's edge row

  const char* wp3b = (const char*)Wp3;
  auto stage = [&](int bufi, int ntc){            // 16 KB chunk = nt {2ntc, 2ntc+1}
    const char* src = wp3b + (size_t)ntc * 16384;
    char* dst = (char*)&wS[bufi][0];
#pragma unroll
    for (int c = 0; c < 4; ++c)
      gld16(src + (w * 4 + c) * 1024 + l * 16, dst + (w * 4 + c) * 1024);
  };

  stage(0, 0);   // first W chunk DMA overlaps the edge burst

  // edge A-frags: two bulk groups of 8 dwordx4 (32 VGPR in flight each)
  bf16x8 af[8];
  {
    const float* ap = edges + (size_t)bi * 16384 + (size_t)j * 256 + lq * 8;
    float4 x[4], y[4];
#pragma unroll
    for (int kk = 0; kk < 4; kk++){
      x[kk] = *(const float4*)(ap + kk * 32);
      y[kk] = *(const float4*)(ap + kk * 32 + 4);
    }
#pragma unroll
    for (int kk = 0; kk < 4; kk++){
      bf16x8 a;
      a[0]=(short)f2bfu(x[kk].x); a[1]=(short)f2bfu(x[kk].y); a[2]=(short)f2bfu(x[kk].z); a[3]=(short)f2bfu(x[kk].w);
      a[4]=(short)f2bfu(y[kk].x); a[5]=(short)f2bfu(y[kk].y); a[6]=(short)f2bfu(y[kk].z); a[7]=(short)f2bfu(y[kk].w);
      af[kk] = a;
    }
#pragma unroll
    for (int kk = 0; kk < 4; kk++){
      x[kk] = *(const float4*)(ap + (kk + 4) * 32);
      y[kk] = *(const float4*)(ap + (kk + 4) * 32 + 4);
    }
#pragma unroll
    for (int kk = 0; kk < 4; kk++){
      bf16x8 a;
      a[0]=(short)f2bfu(x[kk].x); a[1]=(short)f2bfu(x[kk].y); a[2]=(short)f2bfu(x[kk].z); a[3]=(short)f2bfu(x[kk].w);
      a[4]=(short)f2bfu(y[kk].x); a[5]=(short)f2bfu(y[kk].y); a[6]=(short)f2bfu(y[kk].z); a[7]=(short)f2bfu(y[kk].w);
      af[kk + 4] = a;
    }
  }

  const float* p1p = P1 + (size_t)bi * 256;
  const float* p2p = P2 + ((size_t)b * 64 + j) * 256;
  float* hop = out_h + ((size_t)bi * 64 + j) * 256;
  float cpart = 0.f;

  __syncthreads();                    // chunk 0 staged
  int buf = 0;
#pragma unroll
  for (int ntc = 0; ntc < 8; ntc++){
    if (ntc < 7) stage(buf ^ 1, ntc + 1);
#pragma unroll
    for (int nt2 = 0; nt2 < 2; nt2++){
      const int nt = ntc * 2 + nt2;
      f32x4 acc = {0.f, 0.f, 0.f, 0.f};          // chunk-local accumulator
#pragma unroll
      for (int kk = 0; kk < 8; kk++){
        BU bu; bu.v = wS[buf][(nt2 * 8 + kk) * 64 + l];
        acc = __builtin_amdgcn_mfma_f32_16x16x32_bf16(bu.s, af[kk], acc, 0, 0, 0);
      }
      // epilogue for this 16-col slab: +P1+P2, relu, vectorized h store
      const int d0 = nt * 16 + 4 * lq;
      f4 p1v = *(const f4*)(p1p + d0);
      f4 p2v = *(const f4*)(p2p + d0);
      f4 wcv = *(const f4*)(W_coef + d0);
      f4 h;
#pragma unroll
      for (int r = 0; r < 4; r++){
        float xx = acc[r] + p1v[r] + p2v[r];
        h[r] = xx > 0.f ? xx : 0.f;
      }
      *(f4*)(hop + d0) = h;
      cpart += h[0]*wcv[0] + h[1]*wcv[1] + h[2]*wcv[2] + h[3]*wcv[3];
    }
    __syncthreads();
    buf ^= 1;
  }

  // coef[j] partial: sum over the 4 lq groups (lanes l^16, l^32 share j)
  cpart += __shfl_xor(cpart, 16, 64);
  cpart += __shfl_xor(cpart, 32, 64);
  if (lq == 0) coefW[(size_t)bi * 64 + j] = cpart;
}

// ---------------- k_attn: softmax + residual + W_out ------------------------
// bi order REVERSED within each XCD chunk: most-recently-written h read first
// (LIFO locality in L2/L3). Pure streaming, no MFMA, 2 barriers.
__global__ __launch_bounds__(256) void k_attn(
    const float* __restrict__ nodes, const float* __restrict__ coefW,
    const float* __restrict__ b_coef, const float* __restrict__ W_out,
    const float* __restrict__ b_out, const float* __restrict__ h_in,
    float* __restrict__ out_nodes)
{
  __shared__ float attnS[64];
  __shared__ float resS[256];

  const int t = threadIdx.x;
  const int bid = blockIdx.x;
  const int bi = ((bid & 7) << 7) | (127 - (bid >> 3));   // reversed within XCD chunk
  const int i = bi & 63;

  if (t < 64){
    float val = coefW[(size_t)bi * 64 + t] + b_coef[0] - (t == i ? 1e9f : 0.f);
    float m = val;
#pragma unroll
    for (int off = 32; off >= 1; off >>= 1){ float o = __shfl_xor(m, off, 64); m = m > o ? m : o; }
    float e = __expf(val - m);
    float s = e;
#pragma unroll
    for (int off = 32; off >= 1; off >>= 1) s += __shfl_xor(s, off, 64);
    attnS[t] = e / s;
  }
  __syncthreads();

  // residual[d=t] = sum_j attn[j] * h[j][d]
  {
    const float* hb = h_in + (size_t)bi * 16384;
    float res = 0.f;
#pragma unroll 8
    for (int jj = 0; jj < 64; jj++) res += attnS[jj] * hb[(size_t)jj * 256 + t];
    resS[t] = res;
  }
  __syncthreads();

  // new_nodes = nodes + relu(res @ W_out + b_out)
  {
    const int d = t;
    float acco = b_out[d];
#pragma unroll 8
    for (int k4 = 0; k4 < 64; k4++){
      float4 r4 = *(const float4*)&resS[k4 * 4];
      acco += r4.x * W_out[(size_t)(k4 * 4 + 0) * 256 + d];
      acco += r4.y * W_out[(size_t)(k4 * 4 + 1) * 256 + d];
      acco += r4.z * W_out[(size_t)(k4 * 4 + 2) * 256 + d];
      acco += r4.w * W_out[(size_t)(k4 * 4 + 3) * 256 + d];
    }
    float nv = nodes[(size_t)bi * 256 + d];
    out_nodes[(size_t)bi * 256 + d] = nv + (acco > 0.f ? acco : 0.f);
  }
}

extern "C" void kernel_launch(void* const* d_in, const int* in_sizes, int n_in,
                              void* d_out, int out_size, void* d_ws, size_t ws_size,
                              hipStream_t stream)
{
  const float* nodes  = (const float*)d_in[0];
  const float* edges  = (const float*)d_in[1];
  const float* W_in   = (const float*)d_in[2];
  const float* b_in   = (const float*)d_in[3];
  const float* W_coef = (const float*)d_in[4];
  const float* b_coef = (const float*)d_in[5];
  const float* W_out  = (const float*)d_in[6];
  const float* b_out  = (const float*)d_in[7];
  (void)in_sizes; (void)n_in; (void)out_size; (void)ws_size;

  float* P1  = (float*)d_ws;           // [1024][256] f32
  float* P2  = P1 + 262144;            // [1024][256] f32
  u16*  Wp3  = (u16*)(P2 + 262144);    // 65536 bf16 (128 KB)
  u16*  Wp12 = Wp3 + 65536;            // 131072 bf16 (256 KB)
  float* coefW = (float*)(Wp12 + 131072);   // [1024][64] f32 (256 KB)

  float* out_nodes = (float*)d_out;          // [1024*256] f32
  float* out_h = out_nodes + 262144;         // [65536*256] f32

  hipLaunchKernelGGL(k_pack, dim3(96),   dim3(256), 0, stream, W_in, Wp3, Wp12);
  hipLaunchKernelGGL(k_pre,  dim3(128),  dim3(256), 0, stream, nodes, b_in, Wp12, P1, P2);
  hipLaunchKernelGGL(k_h,    dim3(1024), dim3(256), 0, stream,
                     edges, Wp3, W_coef, P1, P2, out_h, coefW);
  hipLaunchKernelGGL(k_attn, dim3(1024), dim3(256), 0, stream,
                     nodes, coefW, b_coef, W_out, b_out, out_h, out_nodes);
}